// Round 1
// baseline (1003.536 us; speedup 1.0000x reference)
//
#include <hip/hip_runtime.h>
#include <hip/hip_bf16.h>
#include <stdint.h>

// Problem dims (fixed)
#define BB 32
#define TT 2048
#define DD 1024
#define DIMQ 1024
#define MTOT (BB*TT)   // 65536 rows of X flattened

typedef __attribute__((ext_vector_type(8))) __bf16 bf16x8;
typedef __attribute__((ext_vector_type(4))) float f32x4;

__device__ __forceinline__ unsigned short f2bf(float f) {
    unsigned int u = __float_as_uint(f);
    u += 0x7FFF + ((u >> 16) & 1);   // round-to-nearest-even
    return (unsigned short)(u >> 16);
}
__device__ __forceinline__ float bf2f(unsigned short s) {
    return __uint_as_float(((unsigned int)s) << 16);
}

__device__ __forceinline__ void load_lds16(const void* g, void* l) {
    __builtin_amdgcn_global_load_lds(
        (const __attribute__((address_space(1))) unsigned int*)g,
        (__attribute__((address_space(3))) unsigned int*)l,
        16, 0, 0);
}

// ---------------- K0: cast X f32 -> bf16 ----------------
__global__ void cast_x(const float* __restrict__ x, unsigned short* __restrict__ xb) {
    long i = ((long)blockIdx.x * blockDim.x + threadIdx.x) * 8;
    float4 a = *(const float4*)(x + i);
    float4 b = *(const float4*)(x + i + 4);
    uint4 o;
    o.x = (unsigned int)f2bf(a.x) | ((unsigned int)f2bf(a.y) << 16);
    o.y = (unsigned int)f2bf(a.z) | ((unsigned int)f2bf(a.w) << 16);
    o.z = (unsigned int)f2bf(b.x) | ((unsigned int)f2bf(b.y) << 16);
    o.w = (unsigned int)f2bf(b.z) | ((unsigned int)f2bf(b.w) << 16);
    *(uint4*)(xb + i) = o;
}

// ---------------- K0b: Wy (D x DIM) f32 -> WyT (DIM x D) bf16 ----------------
__global__ void transpose_cast(const float* __restrict__ Wsrc, unsigned short* __restrict__ Wdst) {
    __shared__ float tile[32][33];
    int bx = blockIdx.x * 32;           // col (e) base
    int by = blockIdx.y * 32;           // row (d) base
    int tx = threadIdx.x & 31;
    int ty4 = (threadIdx.x >> 5) * 4;
    #pragma unroll
    for (int r = 0; r < 4; r++)
        tile[ty4 + r][tx] = Wsrc[(size_t)(by + ty4 + r) * DIMQ + bx + tx];
    __syncthreads();
    #pragma unroll
    for (int r = 0; r < 4; r++)
        Wdst[(size_t)(bx + ty4 + r) * DD + by + tx] = f2bf(tile[tx][ty4 + r]);
}

// ---------------- K1: out[b,e] = sum_d v[b,d] * Mat[d,e] ----------------
__global__ void vecmat(const float* __restrict__ v, const float* __restrict__ Mat,
                       float* __restrict__ out) {
    __shared__ float vs[DD];
    int b = blockIdx.y;
    int e = blockIdx.x * 256 + threadIdx.x;
    for (int d = threadIdx.x; d < DD; d += 256) vs[d] = v[b * DD + d];
    __syncthreads();
    float acc = 0.f;
    #pragma unroll 4
    for (int d = 0; d < DD; d++) acc += vs[d] * Mat[(size_t)d * DIMQ + e];
    out[b * DIMQ + e] = acc;
}

// ---------------- K2: fused GEMM + relu·w reduce -> partial scores ----------------
// C = X(65536x1024) * Wy(1024x1024); partial[ntile][row] = sum_{n in tile} relu(C+hproj)*w
__global__ void gemm_scores(const unsigned short* __restrict__ Xb,
                            const unsigned short* __restrict__ WyT,
                            const float* __restrict__ hproj,
                            const float* __restrict__ wvec,
                            float* __restrict__ partials) {
    __shared__ unsigned short Alds[4096];   // 8 subtiles * 64 lanes * 8 bf16 (frag order)
    __shared__ unsigned short Blds[4096];
    __shared__ float lp[128];

    int x = blockIdx.x;
    int mtile = x >> 3, ntile = x & 7;
    int tid = threadIdx.x;
    int lane = tid & 63;
    int wave = tid >> 6;

    if (tid < 128) lp[tid] = 0.f;

    const int rowA0 = mtile * 128;
    const int colB0 = ntile * 128;

    // staging chunk precompute (c0 = tid, c1 = tid + 256)
    int sub0 = tid >> 6,          ln0 = tid & 63;
    int r0 = sub0 * 16 + (ln0 & 15), ko0 = (ln0 >> 4) << 3;
    int sub1 = (tid + 256) >> 6,  ln1 = (tid + 256) & 63;
    int r1 = sub1 * 16 + (ln1 & 15), ko1 = (ln1 >> 4) << 3;

    const unsigned short* Ag0 = Xb  + (size_t)(rowA0 + r0) * DD + ko0;
    const unsigned short* Ag1 = Xb  + (size_t)(rowA0 + r1) * DD + ko1;
    const unsigned short* Bg0 = WyT + (size_t)(colB0 + r0) * DD + ko0;
    const unsigned short* Bg1 = WyT + (size_t)(colB0 + r1) * DD + ko1;

    unsigned short* Al0 = &Alds[tid * 8];
    unsigned short* Al1 = &Alds[(tid + 256) * 8];
    unsigned short* Bl0 = &Blds[tid * 8];
    unsigned short* Bl1 = &Blds[(tid + 256) * 8];

    int wm = (wave >> 1) * 4;   // A subtile base (0 or 4)
    int wn = (wave & 1) * 4;    // B subtile base (0 or 4)

    f32x4 acc[4][4] = {};

    for (int kk = 0; kk < DD; kk += 32) {
        load_lds16(Ag0 + kk, Al0);
        load_lds16(Ag1 + kk, Al1);
        load_lds16(Bg0 + kk, Bl0);
        load_lds16(Bg1 + kk, Bl1);
        __syncthreads();   // drains vmcnt -> LDS visible

        bf16x8 af[4], bfr[4];
        #pragma unroll
        for (int i = 0; i < 4; i++)
            af[i] = *reinterpret_cast<const bf16x8*>(&Alds[((wm + i) * 64 + lane) * 8]);
        #pragma unroll
        for (int j = 0; j < 4; j++)
            bfr[j] = *reinterpret_cast<const bf16x8*>(&Blds[((wn + j) * 64 + lane) * 8]);
        #pragma unroll
        for (int i = 0; i < 4; i++)
            #pragma unroll
            for (int j = 0; j < 4; j++)
                acc[i][j] = __builtin_amdgcn_mfma_f32_16x16x32_bf16(af[i], bfr[j], acc[i][j], 0, 0, 0);
        __syncthreads();   // before next overwrite
    }

    // Epilogue: partial score = sum_n relu(acc + hproj[b,n]) * w[n]
    int b = rowA0 / TT;
    int q = lane >> 4, l15 = lane & 15;
    int wmRow = (wave >> 1) * 64, wnCol = (wave & 1) * 64;

    float hpv[4], wvv[4];
    #pragma unroll
    for (int j = 0; j < 4; j++) {
        int n = wnCol + j * 16 + l15;
        hpv[j] = hproj[b * DIMQ + colB0 + n];
        wvv[j] = wvec[colB0 + n];
    }

    #pragma unroll
    for (int i = 0; i < 4; i++) {
        f32x4 s = {0.f, 0.f, 0.f, 0.f};
        #pragma unroll
        for (int j = 0; j < 4; j++) {
            #pragma unroll
            for (int r = 0; r < 4; r++) {
                float v = acc[i][j][r] + hpv[j];
                v = v > 0.f ? v : 0.f;
                s[r] += v * wvv[j];
            }
        }
        #pragma unroll
        for (int off = 1; off < 16; off <<= 1) {
            s[0] += __shfl_xor(s[0], off);
            s[1] += __shfl_xor(s[1], off);
            s[2] += __shfl_xor(s[2], off);
            s[3] += __shfl_xor(s[3], off);
        }
        if (l15 == 0) {
            int mrow = wmRow + i * 16 + q * 4;
            atomicAdd(&lp[mrow + 0], s[0]);
            atomicAdd(&lp[mrow + 1], s[1]);
            atomicAdd(&lp[mrow + 2], s[2]);
            atomicAdd(&lp[mrow + 3], s[3]);
        }
    }
    __syncthreads();
    if (tid < 128)
        partials[(size_t)ntile * MTOT + rowA0 + tid] = lp[tid];
}

// ---------------- K3: sum partials, softmax over T, write alpha ----------------
__global__ void softmax_alpha(const float* __restrict__ partials, float* __restrict__ alpha) {
    __shared__ float wred[4];
    __shared__ float wsum[4];
    int b = blockIdx.x;
    int tid = threadIdx.x;
    float s[8];
    float mx = -1e30f;
    #pragma unroll
    for (int c = 0; c < 8; c++) {
        int t = tid + c * 256;
        float v = 0.f;
        #pragma unroll
        for (int p = 0; p < 8; p++) v += partials[(size_t)p * MTOT + b * TT + t];
        s[c] = v;
        mx = fmaxf(mx, v);
    }
    for (int off = 32; off; off >>= 1) mx = fmaxf(mx, __shfl_xor(mx, off));
    if ((tid & 63) == 0) wred[tid >> 6] = mx;
    __syncthreads();
    mx = fmaxf(fmaxf(wred[0], wred[1]), fmaxf(wred[2], wred[3]));
    float sum = 0.f;
    #pragma unroll
    for (int c = 0; c < 8; c++) { s[c] = expf(s[c] - mx); sum += s[c]; }
    for (int off = 32; off; off >>= 1) sum += __shfl_xor(sum, off);
    if ((tid & 63) == 0) wsum[tid >> 6] = sum;
    __syncthreads();
    sum = wsum[0] + wsum[1] + wsum[2] + wsum[3];
    float inv = 1.f / sum;
    #pragma unroll
    for (int c = 0; c < 8; c++) alpha[b * TT + tid + c * 256] = s[c] * inv;
}

// ---------------- K4: r_part[tc][b][d] = sum_{t in chunk} alpha * X ----------------
__global__ void weighted_sum(const unsigned short* __restrict__ Xb,
                             const float* __restrict__ alpha,
                             float* __restrict__ r_part) {
    __shared__ float al[256];
    int tc = blockIdx.x, b = blockIdx.y, tid = threadIdx.x;
    al[tid] = alpha[b * TT + tc * 256 + tid];
    __syncthreads();
    int d0 = tid * 4;
    const unsigned short* base = Xb + ((size_t)(b * TT + tc * 256)) * DD + d0;
    f32x4 acc = {0.f, 0.f, 0.f, 0.f};
    for (int t = 0; t < 256; t++) {
        ushort4 xv = *(const ushort4*)(base + (size_t)t * DD);
        float a_ = al[t];
        acc[0] += a_ * bf2f(xv.x);
        acc[1] += a_ * bf2f(xv.y);
        acc[2] += a_ * bf2f(xv.z);
        acc[3] += a_ * bf2f(xv.w);
    }
    float* o = r_part + ((size_t)tc * BB + b) * DD + d0;
    o[0] = acc[0]; o[1] = acc[1]; o[2] = acc[2]; o[3] = acc[3];
}

// ---------------- K5: out = relu(r @ Wp + lsWx) ----------------
__global__ void final_out(const float* __restrict__ r_part, const float* __restrict__ Wp,
                          const float* __restrict__ lsWx, float* __restrict__ out) {
    __shared__ float rs[DD];
    int b = blockIdx.y;
    int e = blockIdx.x * 256 + threadIdx.x;
    for (int d = threadIdx.x; d < DD; d += 256) {
        float v = 0.f;
        #pragma unroll
        for (int p = 0; p < 8; p++) v += r_part[((size_t)p * BB + b) * DD + d];
        rs[d] = v;
    }
    __syncthreads();
    float acc = lsWx[b * DIMQ + e];
    #pragma unroll 4
    for (int d = 0; d < DD; d++) acc += rs[d] * Wp[(size_t)d * DIMQ + e];
    out[b * DIMQ + e] = fmaxf(acc, 0.f);
}

extern "C" void kernel_launch(void* const* d_in, const int* in_sizes, int n_in,
                              void* d_out, int out_size, void* d_ws, size_t ws_size,
                              hipStream_t stream) {
    const float* x    = (const float*)d_in[0];  // (B,T,D)
    const float* last = (const float*)d_in[1];  // (B,D)
    const float* Wy   = (const float*)d_in[2];  // (D,DIM)
    const float* Wh   = (const float*)d_in[3];  // (D,DIM)
    const float* w    = (const float*)d_in[4];  // (DIM,1)
    const float* Wp   = (const float*)d_in[5];  // (D,DIM)
    const float* Wx   = (const float*)d_in[6];  // (D,DIM)
    float* out = (float*)d_out;

    // workspace layout (needs ~134 MiB)
    char* ws = (char*)d_ws;
    unsigned short* Xb   = (unsigned short*)(ws);                  // 128 MiB
    unsigned short* WyT  = (unsigned short*)(ws + 134217728);      // 2 MiB
    float* hproj         = (float*)(ws + 136314880);               // 128 KiB
    float* lsWx          = (float*)(ws + 136445952);               // 128 KiB
    float* partials      = (float*)(ws + 136577024);               // 2 MiB
    float* alpha         = (float*)(ws + 138674176);               // 256 KiB
    float* r_part        = (float*)(ws + 138936320);               // 1 MiB

    cast_x<<<(BB*TT*DD/8 + 255) / 256, 256, 0, stream>>>(x, Xb);
    transpose_cast<<<dim3(32, 32), 256, 0, stream>>>(Wy, WyT);
    vecmat<<<dim3(4, BB), 256, 0, stream>>>(last, Wh, hproj);
    vecmat<<<dim3(4, BB), 256, 0, stream>>>(last, Wx, lsWx);
    gemm_scores<<<512 * 8, 256, 0, stream>>>(Xb, WyT, hproj, w, partials);
    softmax_alpha<<<BB, 256, 0, stream>>>(partials, alpha);
    weighted_sum<<<dim3(8, BB), 256, 0, stream>>>(Xb, alpha, r_part);
    final_out<<<dim3(4, BB), 256, 0, stream>>>(r_part, Wp, lsWx, out);
}

// Round 2
// 698.720 us; speedup vs baseline: 1.4362x; 1.4362x over previous
//
#include <hip/hip_runtime.h>
#include <hip/hip_bf16.h>
#include <stdint.h>

// Problem dims (fixed)
#define BB 32
#define TT 2048
#define DD 1024
#define DIMQ 1024
#define MTOT (BB*TT)   // 65536 rows of X flattened

typedef __attribute__((ext_vector_type(8))) __bf16 bf16x8;
typedef __attribute__((ext_vector_type(4))) float f32x4;

__device__ __forceinline__ unsigned short f2bf(float f) {
    unsigned int u = __float_as_uint(f);
    u += 0x7FFF + ((u >> 16) & 1);   // round-to-nearest-even
    return (unsigned short)(u >> 16);
}
__device__ __forceinline__ float bf2f(unsigned short s) {
    return __uint_as_float(((unsigned int)s) << 16);
}

__device__ __forceinline__ void load_lds16(const void* g, void* l) {
    __builtin_amdgcn_global_load_lds(
        (const __attribute__((address_space(1))) unsigned int*)g,
        (__attribute__((address_space(3))) unsigned int*)l,
        16, 0, 0);
}

// ---------------- K0: cast X f32 -> bf16 ----------------
__global__ void cast_x(const float* __restrict__ x, unsigned short* __restrict__ xb) {
    long i = ((long)blockIdx.x * blockDim.x + threadIdx.x) * 8;
    float4 a = *(const float4*)(x + i);
    float4 b = *(const float4*)(x + i + 4);
    uint4 o;
    o.x = (unsigned int)f2bf(a.x) | ((unsigned int)f2bf(a.y) << 16);
    o.y = (unsigned int)f2bf(a.z) | ((unsigned int)f2bf(a.w) << 16);
    o.z = (unsigned int)f2bf(b.x) | ((unsigned int)f2bf(b.y) << 16);
    o.w = (unsigned int)f2bf(b.z) | ((unsigned int)f2bf(b.w) << 16);
    *(uint4*)(xb + i) = o;
}

// ---------------- K0b: Wy (D x DIM) f32 -> WyT (DIM x D) bf16 ----------------
__global__ void transpose_cast(const float* __restrict__ Wsrc, unsigned short* __restrict__ Wdst) {
    __shared__ float tile[32][33];
    int bx = blockIdx.x * 32;           // col (e) base
    int by = blockIdx.y * 32;           // row (d) base
    int tx = threadIdx.x & 31;
    int ty4 = (threadIdx.x >> 5) * 4;
    #pragma unroll
    for (int r = 0; r < 4; r++)
        tile[ty4 + r][tx] = Wsrc[(size_t)(by + ty4 + r) * DIMQ + bx + tx];
    __syncthreads();
    #pragma unroll
    for (int r = 0; r < 4; r++)
        Wdst[(size_t)(bx + ty4 + r) * DD + by + tx] = f2bf(tile[tx][ty4 + r]);
}

// ---------------- K1: fused dual vec-mat, split-K ----------------
// z=0: hproj = last @ Wh ; z=1: lsWx = last @ Wx
// grid (DIMQ/64, BB, 2), 256 thr: e = tid&63, dgroup = tid>>6 covers 256 d's
__global__ void vecmat2(const float* __restrict__ last,
                        const float* __restrict__ Wh, const float* __restrict__ Wx,
                        float* __restrict__ hproj, float* __restrict__ lsWx) {
    __shared__ float vs[DD];
    __shared__ float red[4][64];
    int b = blockIdx.y;
    int e0 = blockIdx.x * 64;
    const float* Mat = blockIdx.z ? Wx : Wh;
    float* outp = blockIdx.z ? lsWx : hproj;
    int tid = threadIdx.x;
    for (int d = tid; d < DD; d += 256) vs[d] = last[b * DD + d];
    __syncthreads();
    int e = tid & 63, dg = tid >> 6;
    int d0 = dg * 256;
    const float* Mp = Mat + (size_t)d0 * DIMQ + e0 + e;
    float acc = 0.f;
    #pragma unroll 8
    for (int d = 0; d < 256; d++) acc += vs[d0 + d] * Mp[(size_t)d * DIMQ];
    red[dg][e] = acc;
    __syncthreads();
    if (dg == 0)
        outp[b * DIMQ + e0 + e] = red[0][e] + red[1][e] + red[2][e] + red[3][e];
}

// ---------------- K2: fused GEMM + relu·w reduce -> partial scores ----------------
__global__ void gemm_scores(const unsigned short* __restrict__ Xb,
                            const unsigned short* __restrict__ WyT,
                            const float* __restrict__ hproj,
                            const float* __restrict__ wvec,
                            float* __restrict__ partials) {
    __shared__ unsigned short Alds[4096];   // 8 subtiles * 64 lanes * 8 bf16 (frag order)
    __shared__ unsigned short Blds[4096];
    __shared__ float lp[128];

    int x = blockIdx.x;
    int mtile = x >> 3, ntile = x & 7;
    int tid = threadIdx.x;
    int lane = tid & 63;
    int wave = tid >> 6;

    if (tid < 128) lp[tid] = 0.f;

    const int rowA0 = mtile * 128;
    const int colB0 = ntile * 128;

    int sub0 = tid >> 6,          ln0 = tid & 63;
    int r0 = sub0 * 16 + (ln0 & 15), ko0 = (ln0 >> 4) << 3;
    int sub1 = (tid + 256) >> 6,  ln1 = (tid + 256) & 63;
    int r1 = sub1 * 16 + (ln1 & 15), ko1 = (ln1 >> 4) << 3;

    const unsigned short* Ag0 = Xb  + (size_t)(rowA0 + r0) * DD + ko0;
    const unsigned short* Ag1 = Xb  + (size_t)(rowA0 + r1) * DD + ko1;
    const unsigned short* Bg0 = WyT + (size_t)(colB0 + r0) * DD + ko0;
    const unsigned short* Bg1 = WyT + (size_t)(colB0 + r1) * DD + ko1;

    unsigned short* Al0 = &Alds[tid * 8];
    unsigned short* Al1 = &Alds[(tid + 256) * 8];
    unsigned short* Bl0 = &Blds[tid * 8];
    unsigned short* Bl1 = &Blds[(tid + 256) * 8];

    int wm = (wave >> 1) * 4;
    int wn = (wave & 1) * 4;

    f32x4 acc[4][4] = {};

    for (int kk = 0; kk < DD; kk += 32) {
        load_lds16(Ag0 + kk, Al0);
        load_lds16(Ag1 + kk, Al1);
        load_lds16(Bg0 + kk, Bl0);
        load_lds16(Bg1 + kk, Bl1);
        __syncthreads();

        bf16x8 af[4], bfr[4];
        #pragma unroll
        for (int i = 0; i < 4; i++)
            af[i] = *reinterpret_cast<const bf16x8*>(&Alds[((wm + i) * 64 + lane) * 8]);
        #pragma unroll
        for (int j = 0; j < 4; j++)
            bfr[j] = *reinterpret_cast<const bf16x8*>(&Blds[((wn + j) * 64 + lane) * 8]);
        #pragma unroll
        for (int i = 0; i < 4; i++)
            #pragma unroll
            for (int j = 0; j < 4; j++)
                acc[i][j] = __builtin_amdgcn_mfma_f32_16x16x32_bf16(af[i], bfr[j], acc[i][j], 0, 0, 0);
        __syncthreads();
    }

    int b = rowA0 / TT;
    int q = lane >> 4, l15 = lane & 15;
    int wmRow = (wave >> 1) * 64, wnCol = (wave & 1) * 64;

    float hpv[4], wvv[4];
    #pragma unroll
    for (int j = 0; j < 4; j++) {
        int n = wnCol + j * 16 + l15;
        hpv[j] = hproj[b * DIMQ + colB0 + n];
        wvv[j] = wvec[colB0 + n];
    }

    #pragma unroll
    for (int i = 0; i < 4; i++) {
        f32x4 s = {0.f, 0.f, 0.f, 0.f};
        #pragma unroll
        for (int j = 0; j < 4; j++) {
            #pragma unroll
            for (int r = 0; r < 4; r++) {
                float v = acc[i][j][r] + hpv[j];
                v = v > 0.f ? v : 0.f;
                s[r] += v * wvv[j];
            }
        }
        #pragma unroll
        for (int off = 1; off < 16; off <<= 1) {
            s[0] += __shfl_xor(s[0], off);
            s[1] += __shfl_xor(s[1], off);
            s[2] += __shfl_xor(s[2], off);
            s[3] += __shfl_xor(s[3], off);
        }
        if (l15 == 0) {
            int mrow = wmRow + i * 16 + q * 4;
            atomicAdd(&lp[mrow + 0], s[0]);
            atomicAdd(&lp[mrow + 1], s[1]);
            atomicAdd(&lp[mrow + 2], s[2]);
            atomicAdd(&lp[mrow + 3], s[3]);
        }
    }
    __syncthreads();
    if (tid < 128)
        partials[(size_t)ntile * MTOT + rowA0 + tid] = lp[tid];
}

// ---------------- K3a: scores = sum_p partials ----------------
__global__ void sum_partials(const float* __restrict__ partials, float* __restrict__ scores) {
    int i0 = (blockIdx.x * 256 + threadIdx.x) * 4;
    float4 v = {0.f, 0.f, 0.f, 0.f};
    #pragma unroll
    for (int p = 0; p < 8; p++) {
        float4 t = *(const float4*)(partials + (size_t)p * MTOT + i0);
        v.x += t.x; v.y += t.y; v.z += t.z; v.w += t.w;
    }
    *(float4*)(scores + i0) = v;
}

// ---------------- K3b: softmax over T ----------------
__global__ void softmax_alpha(const float* __restrict__ scores, float* __restrict__ alpha) {
    __shared__ float wred[4];
    __shared__ float wsum[4];
    int b = blockIdx.x;
    int tid = threadIdx.x;
    float s[8];
    float mx = -1e30f;
    #pragma unroll
    for (int c = 0; c < 8; c++) {
        float v = scores[b * TT + tid + c * 256];
        s[c] = v;
        mx = fmaxf(mx, v);
    }
    for (int off = 32; off; off >>= 1) mx = fmaxf(mx, __shfl_xor(mx, off));
    if ((tid & 63) == 0) wred[tid >> 6] = mx;
    __syncthreads();
    mx = fmaxf(fmaxf(wred[0], wred[1]), fmaxf(wred[2], wred[3]));
    float sum = 0.f;
    #pragma unroll
    for (int c = 0; c < 8; c++) { s[c] = expf(s[c] - mx); sum += s[c]; }
    for (int off = 32; off; off >>= 1) sum += __shfl_xor(sum, off);
    if ((tid & 63) == 0) wsum[tid >> 6] = sum;
    __syncthreads();
    sum = wsum[0] + wsum[1] + wsum[2] + wsum[3];
    float inv = 1.f / sum;
    #pragma unroll
    for (int c = 0; c < 8; c++) alpha[b * TT + tid + c * 256] = s[c] * inv;
}

// ---------------- K4: r_part[tc][b][d] = sum_{t in 128-chunk} alpha * X ----------------
// grid (T/128, B), 256 thr, 4 d's per thread
__global__ void weighted_sum(const unsigned short* __restrict__ Xb,
                             const float* __restrict__ alpha,
                             float* __restrict__ r_part) {
    __shared__ float al[128];
    int tc = blockIdx.x, b = blockIdx.y, tid = threadIdx.x;
    if (tid < 128) al[tid] = alpha[b * TT + tc * 128 + tid];
    __syncthreads();
    int d0 = tid * 4;
    const unsigned short* base = Xb + ((size_t)(b * TT + tc * 128)) * DD + d0;
    f32x4 acc = {0.f, 0.f, 0.f, 0.f};
    #pragma unroll 2
    for (int t = 0; t < 128; t++) {
        ushort4 xv = *(const ushort4*)(base + (size_t)t * DD);
        float a_ = al[t];
        acc[0] += a_ * bf2f(xv.x);
        acc[1] += a_ * bf2f(xv.y);
        acc[2] += a_ * bf2f(xv.z);
        acc[3] += a_ * bf2f(xv.w);
    }
    float* o = r_part + ((size_t)tc * BB + b) * DD + d0;
    *(float4*)o = *(float4*)&acc;
}

// ---------------- K4b: r[b,d] = sum_tc r_part ----------------
__global__ void reduce_r(const float* __restrict__ r_part, float* __restrict__ rbuf) {
    int b = blockIdx.x, tid = threadIdx.x;
    int d0 = tid * 4;
    float4 v = {0.f, 0.f, 0.f, 0.f};
    #pragma unroll
    for (int p = 0; p < 16; p++) {
        float4 t = *(const float4*)(r_part + ((size_t)p * BB + b) * DD + d0);
        v.x += t.x; v.y += t.y; v.z += t.z; v.w += t.w;
    }
    *(float4*)(rbuf + b * DD + d0) = v;
}

// ---------------- K5: out = relu(r @ Wp + lsWx), split-K ----------------
// grid (DIMQ/64, BB), 256 thr: e = tid&63, dgroup = tid>>6 covers 256 d's
__global__ void final_out(const float* __restrict__ rbuf, const float* __restrict__ Wp,
                          const float* __restrict__ lsWx, float* __restrict__ out) {
    __shared__ float rs[DD];
    __shared__ float red[4][64];
    int b = blockIdx.y;
    int e0 = blockIdx.x * 64;
    int tid = threadIdx.x;
    for (int d = tid; d < DD; d += 256) rs[d] = rbuf[b * DD + d];
    __syncthreads();
    int e = tid & 63, dg = tid >> 6;
    int d0 = dg * 256;
    const float* Mp = Wp + (size_t)d0 * DIMQ + e0 + e;
    float acc = 0.f;
    #pragma unroll 8
    for (int d = 0; d < 256; d++) acc += rs[d0 + d] * Mp[(size_t)d * DIMQ];
    red[dg][e] = acc;
    __syncthreads();
    if (dg == 0) {
        float v = red[0][e] + red[1][e] + red[2][e] + red[3][e]
                + lsWx[b * DIMQ + e0 + e];
        out[b * DIMQ + e0 + e] = fmaxf(v, 0.f);
    }
}

extern "C" void kernel_launch(void* const* d_in, const int* in_sizes, int n_in,
                              void* d_out, int out_size, void* d_ws, size_t ws_size,
                              hipStream_t stream) {
    const float* x    = (const float*)d_in[0];  // (B,T,D)
    const float* last = (const float*)d_in[1];  // (B,D)
    const float* Wy   = (const float*)d_in[2];  // (D,DIM)
    const float* Wh   = (const float*)d_in[3];  // (D,DIM)
    const float* w    = (const float*)d_in[4];  // (DIM,1)
    const float* Wp   = (const float*)d_in[5];  // (D,DIM)
    const float* Wx   = (const float*)d_in[6];  // (D,DIM)
    float* out = (float*)d_out;

    // workspace layout (~136 MiB)
    char* ws = (char*)d_ws;
    unsigned short* Xb   = (unsigned short*)(ws);                  // 128 MiB
    unsigned short* WyT  = (unsigned short*)(ws + 134217728);      // 2 MiB
    float* hproj         = (float*)(ws + 136314880);               // 128 KiB
    float* lsWx          = (float*)(ws + 136445952);               // 128 KiB
    float* partials      = (float*)(ws + 136577024);               // 2 MiB
    float* scores        = (float*)(ws + 138674176);               // 256 KiB
    float* alpha         = (float*)(ws + 138936320);               // 256 KiB
    float* r_part        = (float*)(ws + 139198464);               // 2 MiB
    float* rbuf          = (float*)(ws + 141295616);               // 128 KiB

    cast_x<<<(BB*TT*DD/8 + 255) / 256, 256, 0, stream>>>(x, Xb);
    transpose_cast<<<dim3(32, 32), 256, 0, stream>>>(Wy, WyT);
    vecmat2<<<dim3(DIMQ/64, BB, 2), 256, 0, stream>>>(last, Wh, Wx, hproj, lsWx);
    gemm_scores<<<512 * 8, 256, 0, stream>>>(Xb, WyT, hproj, w, partials);
    sum_partials<<<MTOT/(256*4), 256, 0, stream>>>(partials, scores);
    softmax_alpha<<<BB, 256, 0, stream>>>(scores, alpha);
    weighted_sum<<<dim3(TT/128, BB), 256, 0, stream>>>(Xb, alpha, r_part);
    reduce_r<<<BB, 256, 0, stream>>>(r_part, rbuf);
    final_out<<<dim3(DIMQ/64, BB), 256, 0, stream>>>(rbuf, Wp, lsWx, out);
}

// Round 3
// 643.614 us; speedup vs baseline: 1.5592x; 1.0856x over previous
//
#include <hip/hip_runtime.h>
#include <hip/hip_bf16.h>
#include <stdint.h>

// Problem dims (fixed)
#define BB 32
#define TT 2048
#define DD 1024
#define DIMQ 1024
#define MTOT (BB*TT)   // 65536 rows of X flattened

typedef __attribute__((ext_vector_type(8))) __bf16 bf16x8;
typedef __attribute__((ext_vector_type(4))) float f32x4;

__device__ __forceinline__ unsigned short f2bf(float f) {
    unsigned int u = __float_as_uint(f);
    u += 0x7FFF + ((u >> 16) & 1);   // round-to-nearest-even
    return (unsigned short)(u >> 16);
}
__device__ __forceinline__ float bf2f(unsigned short s) {
    return __uint_as_float(((unsigned int)s) << 16);
}

__device__ __forceinline__ void load_lds16(const void* g, void* l) {
    __builtin_amdgcn_global_load_lds(
        (const __attribute__((address_space(1))) unsigned int*)g,
        (__attribute__((address_space(3))) unsigned int*)l,
        16, 0, 0);
}

// ---------------- K0: cast X f32 -> bf16 (1 float4 per thread, fully coalesced) ----
__global__ void cast_x(const float* __restrict__ x, unsigned short* __restrict__ xb) {
    long i = ((long)blockIdx.x * blockDim.x + threadIdx.x) * 4;
    float4 a = *(const float4*)(x + i);
    ushort4 o;
    o.x = f2bf(a.x); o.y = f2bf(a.y); o.z = f2bf(a.z); o.w = f2bf(a.w);
    *(ushort4*)(xb + i) = o;
}

// ---------------- K0b: Wy (D x DIM) f32 -> WyT (DIM x D) bf16 ----------------
__global__ void transpose_cast(const float* __restrict__ Wsrc, unsigned short* __restrict__ Wdst) {
    __shared__ float tile[32][33];
    int bx = blockIdx.x * 32;           // col (e) base
    int by = blockIdx.y * 32;           // row (d) base
    int tx = threadIdx.x & 31;
    int ty4 = (threadIdx.x >> 5) * 4;
    #pragma unroll
    for (int r = 0; r < 4; r++)
        tile[ty4 + r][tx] = Wsrc[(size_t)(by + ty4 + r) * DIMQ + bx + tx];
    __syncthreads();
    #pragma unroll
    for (int r = 0; r < 4; r++)
        Wdst[(size_t)(bx + ty4 + r) * DD + by + tx] = f2bf(tile[tx][ty4 + r]);
}

// ---------------- K1: fused dual vec-mat, split-K ----------------
__global__ void vecmat2(const float* __restrict__ last,
                        const float* __restrict__ Wh, const float* __restrict__ Wx,
                        float* __restrict__ hproj, float* __restrict__ lsWx) {
    __shared__ float vs[DD];
    __shared__ float red[4][64];
    int b = blockIdx.y;
    int e0 = blockIdx.x * 64;
    const float* Mat = blockIdx.z ? Wx : Wh;
    float* outp = blockIdx.z ? lsWx : hproj;
    int tid = threadIdx.x;
    for (int d = tid; d < DD; d += 256) vs[d] = last[b * DD + d];
    __syncthreads();
    int e = tid & 63, dg = tid >> 6;
    int d0 = dg * 256;
    const float* Mp = Mat + (size_t)d0 * DIMQ + e0 + e;
    float acc = 0.f;
    #pragma unroll 8
    for (int d = 0; d < 256; d++) acc += vs[d0 + d] * Mp[(size_t)d * DIMQ];
    red[dg][e] = acc;
    __syncthreads();
    if (dg == 0)
        outp[b * DIMQ + e0 + e] = red[0][e] + red[1][e] + red[2][e] + red[3][e];
}

// ---------------- K2: fused GEMM + relu·w reduce -> partial scores ----------------
// Block tile 128(M) x 256(N), 4 waves, wave tile 64x128 (4x8 of 16x16x32 MFMA).
// 32 MFMA per wave per K-step (2x round-2) -> fewer barriers per FLOP.
__global__ __launch_bounds__(256, 2)
void gemm_scores(const unsigned short* __restrict__ Xb,
                 const unsigned short* __restrict__ WyT,
                 const float* __restrict__ hproj,
                 const float* __restrict__ wvec,
                 float* __restrict__ partials) {
    __shared__ unsigned short Alds[4096];   // 8 KiB: 8 row-subtiles, frag order
    __shared__ unsigned short Blds[8192];   // 16 KiB: 16 col-subtiles, frag order
    __shared__ float lp[128];

    int x = blockIdx.x;
    int mtile = x >> 2, ntile = x & 3;
    int tid = threadIdx.x;
    int lane = tid & 63;
    int wave = tid >> 6;

    if (tid < 128) lp[tid] = 0.f;

    const int rowA0 = mtile * 128;
    const int colB0 = ntile * 256;

    // Staging: all of a thread's chunks share (lane&15, lane>>4) since chunk
    // ids differ by 256 (== 0 mod 64). A: c=tid, tid+256; B: c=tid+256j.
    int rsel = lane & 15;
    int koff = (lane >> 4) * 8;
    int s0 = tid >> 6;   // 0..3

    const unsigned short* Ag0 = Xb  + (size_t)(rowA0 + s0 * 16 + rsel) * DD + koff;
    const unsigned short* Ag1 = Ag0 + (size_t)64 * DD;
    const unsigned short* Bg0 = WyT + (size_t)(colB0 + s0 * 16 + rsel) * DD + koff;
    const unsigned short* Bg1 = Bg0 + (size_t)64 * DD;
    const unsigned short* Bg2 = Bg0 + (size_t)128 * DD;
    const unsigned short* Bg3 = Bg0 + (size_t)192 * DD;

    unsigned short* Al0 = &Alds[tid * 8];
    unsigned short* Al1 = &Alds[(tid + 256) * 8];
    unsigned short* Bl0 = &Blds[tid * 8];
    unsigned short* Bl1 = &Blds[(tid + 256) * 8];
    unsigned short* Bl2 = &Blds[(tid + 512) * 8];
    unsigned short* Bl3 = &Blds[(tid + 768) * 8];

    int wr = wave >> 1;   // row-half (0..1) -> rows wr*64..wr*64+63
    int wc = wave & 1;    // col-half (0..1) -> cols wc*128..wc*128+127

    f32x4 acc[4][8] = {};

    for (int kk = 0; kk < DD; kk += 32) {
        load_lds16(Ag0 + kk, Al0);
        load_lds16(Ag1 + kk, Al1);
        load_lds16(Bg0 + kk, Bl0);
        load_lds16(Bg1 + kk, Bl1);
        load_lds16(Bg2 + kk, Bl2);
        load_lds16(Bg3 + kk, Bl3);
        __syncthreads();   // drains vmcnt -> LDS visible

        bf16x8 af[4], bfr[8];
        #pragma unroll
        for (int i = 0; i < 4; i++)
            af[i] = *reinterpret_cast<const bf16x8*>(&Alds[((wr * 4 + i) * 64 + lane) * 8]);
        #pragma unroll
        for (int j = 0; j < 8; j++)
            bfr[j] = *reinterpret_cast<const bf16x8*>(&Blds[((wc * 8 + j) * 64 + lane) * 8]);
        #pragma unroll
        for (int i = 0; i < 4; i++)
            #pragma unroll
            for (int j = 0; j < 8; j++)
                acc[i][j] = __builtin_amdgcn_mfma_f32_16x16x32_bf16(af[i], bfr[j], acc[i][j], 0, 0, 0);
        __syncthreads();   // before next overwrite
    }

    // Epilogue: partial score = sum_n relu(acc + hproj[b,n]) * w[n]
    int b = rowA0 / TT;
    int q = lane >> 4, l15 = lane & 15;

    float hpv[8], wvv[8];
    #pragma unroll
    for (int j = 0; j < 8; j++) {
        int n = colB0 + wc * 128 + j * 16 + l15;
        hpv[j] = hproj[b * DIMQ + n];
        wvv[j] = wvec[n];
    }

    #pragma unroll
    for (int i = 0; i < 4; i++) {
        f32x4 s = {0.f, 0.f, 0.f, 0.f};
        #pragma unroll
        for (int j = 0; j < 8; j++) {
            #pragma unroll
            for (int r = 0; r < 4; r++) {
                float v = acc[i][j][r] + hpv[j];
                v = v > 0.f ? v : 0.f;
                s[r] += v * wvv[j];
            }
        }
        #pragma unroll
        for (int off = 1; off < 16; off <<= 1) {
            s[0] += __shfl_xor(s[0], off);
            s[1] += __shfl_xor(s[1], off);
            s[2] += __shfl_xor(s[2], off);
            s[3] += __shfl_xor(s[3], off);
        }
        if (l15 == 0) {
            int mrow = wr * 64 + i * 16 + q * 4;
            atomicAdd(&lp[mrow + 0], s[0]);
            atomicAdd(&lp[mrow + 1], s[1]);
            atomicAdd(&lp[mrow + 2], s[2]);
            atomicAdd(&lp[mrow + 3], s[3]);
        }
    }
    __syncthreads();
    if (tid < 128)
        partials[(size_t)ntile * MTOT + rowA0 + tid] = lp[tid];
}

// ---------------- K3: fused partial-sum + softmax over T ----------------
__global__ void softmax_alpha(const float* __restrict__ partials, float* __restrict__ alpha) {
    __shared__ float wred[4];
    __shared__ float wsum[4];
    int b = blockIdx.x;
    int tid = threadIdx.x;
    float s[8];
    float mx = -1e30f;
    #pragma unroll
    for (int c = 0; c < 8; c++) {
        int t = b * TT + tid + c * 256;
        float v = 0.f;
        #pragma unroll
        for (int p = 0; p < 4; p++) v += partials[(size_t)p * MTOT + t];
        s[c] = v;
        mx = fmaxf(mx, v);
    }
    for (int off = 32; off; off >>= 1) mx = fmaxf(mx, __shfl_xor(mx, off));
    if ((tid & 63) == 0) wred[tid >> 6] = mx;
    __syncthreads();
    mx = fmaxf(fmaxf(wred[0], wred[1]), fmaxf(wred[2], wred[3]));
    float sum = 0.f;
    #pragma unroll
    for (int c = 0; c < 8; c++) { s[c] = expf(s[c] - mx); sum += s[c]; }
    for (int off = 32; off; off >>= 1) sum += __shfl_xor(sum, off);
    if ((tid & 63) == 0) wsum[tid >> 6] = sum;
    __syncthreads();
    sum = wsum[0] + wsum[1] + wsum[2] + wsum[3];
    float inv = 1.f / sum;
    #pragma unroll
    for (int c = 0; c < 8; c++) alpha[b * TT + tid + c * 256] = s[c] * inv;
}

// ---------------- K4: r_part[tc][b][d] = sum_{t in 128-chunk} alpha * X ----------------
__global__ void weighted_sum(const unsigned short* __restrict__ Xb,
                             const float* __restrict__ alpha,
                             float* __restrict__ r_part) {
    __shared__ float al[128];
    int tc = blockIdx.x, b = blockIdx.y, tid = threadIdx.x;
    if (tid < 128) al[tid] = alpha[b * TT + tc * 128 + tid];
    __syncthreads();
    int d0 = tid * 4;
    const unsigned short* base = Xb + ((size_t)(b * TT + tc * 128)) * DD + d0;
    f32x4 acc = {0.f, 0.f, 0.f, 0.f};
    #pragma unroll 2
    for (int t = 0; t < 128; t++) {
        ushort4 xv = *(const ushort4*)(base + (size_t)t * DD);
        float a_ = al[t];
        acc[0] += a_ * bf2f(xv.x);
        acc[1] += a_ * bf2f(xv.y);
        acc[2] += a_ * bf2f(xv.z);
        acc[3] += a_ * bf2f(xv.w);
    }
    float* o = r_part + ((size_t)tc * BB + b) * DD + d0;
    *(float4*)o = *(float4*)&acc;
}

// ---------------- K5: out = relu(r @ Wp + lsWx), fused r-reduce + split-K ----------------
__global__ void final_out(const float* __restrict__ r_part, const float* __restrict__ Wp,
                          const float* __restrict__ lsWx, float* __restrict__ out) {
    __shared__ float rs[DD];
    __shared__ float red[4][64];
    int b = blockIdx.y;
    int e0 = blockIdx.x * 64;
    int tid = threadIdx.x;
    for (int d = tid; d < DD; d += 256) {
        float v = 0.f;
        #pragma unroll
        for (int p = 0; p < 16; p++) v += r_part[((size_t)p * BB + b) * DD + d];
        rs[d] = v;
    }
    __syncthreads();
    int e = tid & 63, dg = tid >> 6;
    int d0 = dg * 256;
    const float* Mp = Wp + (size_t)d0 * DIMQ + e0 + e;
    float acc = 0.f;
    #pragma unroll 8
    for (int d = 0; d < 256; d++) acc += rs[d0 + d] * Mp[(size_t)d * DIMQ];
    red[dg][e] = acc;
    __syncthreads();
    if (dg == 0) {
        float v = red[0][e] + red[1][e] + red[2][e] + red[3][e]
                + lsWx[b * DIMQ + e0 + e];
        out[b * DIMQ + e0 + e] = fmaxf(v, 0.f);
    }
}

extern "C" void kernel_launch(void* const* d_in, const int* in_sizes, int n_in,
                              void* d_out, int out_size, void* d_ws, size_t ws_size,
                              hipStream_t stream) {
    const float* x    = (const float*)d_in[0];  // (B,T,D)
    const float* last = (const float*)d_in[1];  // (B,D)
    const float* Wy   = (const float*)d_in[2];  // (D,DIM)
    const float* Wh   = (const float*)d_in[3];  // (D,DIM)
    const float* w    = (const float*)d_in[4];  // (DIM,1)
    const float* Wp   = (const float*)d_in[5];  // (D,DIM)
    const float* Wx   = (const float*)d_in[6];  // (D,DIM)
    float* out = (float*)d_out;

    // workspace layout (~134 MiB)
    char* ws = (char*)d_ws;
    unsigned short* Xb   = (unsigned short*)(ws);                  // 128 MiB
    unsigned short* WyT  = (unsigned short*)(ws + 134217728);      // 2 MiB
    float* hproj         = (float*)(ws + 136314880);               // 128 KiB
    float* lsWx          = (float*)(ws + 136445952);               // 128 KiB
    float* partials      = (float*)(ws + 136577024);               // 1 MiB (4 x 65536)
    float* alpha         = (float*)(ws + 137625600);               // 256 KiB
    float* r_part        = (float*)(ws + 137887744);               // 2 MiB (16 x 32 x 1024)

    cast_x<<<BB*TT*DD/4/256, 256, 0, stream>>>(x, Xb);
    transpose_cast<<<dim3(32, 32), 256, 0, stream>>>(Wy, WyT);
    vecmat2<<<dim3(DIMQ/64, BB, 2), 256, 0, stream>>>(last, Wh, Wx, hproj, lsWx);
    gemm_scores<<<512 * 4, 256, 0, stream>>>(Xb, WyT, hproj, w, partials);
    softmax_alpha<<<BB, 256, 0, stream>>>(partials, alpha);
    weighted_sum<<<dim3(TT/128, BB), 256, 0, stream>>>(Xb, alpha, r_part);
    final_out<<<dim3(DIMQ/64, BB), 256, 0, stream>>>(r_part, Wp, lsWx, out);
}